// Round 7
// baseline (660.891 us; speedup 1.0000x reference)
//
#include <hip/hip_runtime.h>
#include <hip/hip_bf16.h>

#define BATCH 16
#define NN 1024
#define MM 1024
#define DD 512

#define LOG2E 1.4426950408889634f
#define LN2f  0.6931471805599453f
#define NEGS  -1.442695e9f   // NEG (-1e9) scaled by log2e; acts as -inf sentinel

#define NWAVE 8               // waves per batch
#define DSTAG 96              // inter-wave column stagger (>= barrier period + 64)
#define BARP  32              // barrier period (iters)
#define GTOT  1760            // >= NN-1 + 7*DSTAG + 63 + 2 = 1760, multiple of 8
#define PF    8               // theta prefetch depth (iterations)

typedef __bf16 v8bf __attribute__((ext_vector_type(8)));
typedef __bf16 v4bf __attribute__((ext_vector_type(4)));
typedef float  v4f  __attribute__((ext_vector_type(4)));

// DPP wave shift-right by 1: lane i <- lane i-1 (full-rate VALU, no LDS).
// Lane 0 keeps its own value (bound_ctrl=0, old=src) — always fixed up after.
__device__ __forceinline__ float wave_shr1(float x) {
    int xi = __float_as_int(x);
    int r = __builtin_amdgcn_update_dpp(xi, xi, 0x138, 0xf, 0xf, false);
    return __int_as_float(r);
}

// ---------------------------------------------------------------- zero A acc
__global__ void zero_acc(float* a) {
    if (threadIdx.x < BATCH) a[threadIdx.x] = 0.0f;
}

// ------------------------------------------- fp32->bf16 convert + gap-dot
__global__ __launch_bounds__(256) void conv_reduce(
        const float* __restrict__ zx, const float* __restrict__ zy,
        const float* __restrict__ gw,
        __bf16* __restrict__ zxb, __bf16* __restrict__ zyb,
        float* __restrict__ acc) {
    const int chunk = blockIdx.x, b = blockIdx.y, which = blockIdx.z;
    const float* src = which ? zy : zx;
    __bf16* dst = which ? zyb : zxb;
    const float* g = gw + which * DD;
    const size_t base = ((size_t)b * NN + (size_t)chunk * 64) * DD;
    const int t = threadIdx.x;
    const int col = (t * 4) & (DD - 1);
    const float4 gv = *(const float4*)(g + col);
    float sum = 0.0f;
    #pragma unroll 4
    for (int it = 0; it < 32; ++it) {
        size_t off = base + (size_t)it * 1024 + t * 4;
        float4 x = *(const float4*)(src + off);
        sum += x.x * gv.x + x.y * gv.y + x.z * gv.z + x.w * gv.w;
        v4bf o = { (__bf16)x.x, (__bf16)x.y, (__bf16)x.z, (__bf16)x.w };
        *(v4bf*)(dst + off) = o;
    }
    #pragma unroll
    for (int o = 32; o > 0; o >>= 1) sum += __shfl_down(sum, o);
    __shared__ float wsum[4];
    if ((t & 63) == 0) wsum[t >> 6] = sum;
    __syncthreads();
    if (t == 0) {
        float s = wsum[0] + wsum[1] + wsum[2] + wsum[3];
        atomicAdd(acc + b, s * (1.0f / 1024.0f));
    }
}

// ------------------------------------------------------- bf16 MFMA NT GEMM
// out[row i][col j] = sum_d A[i,d]*B[j,d].  Called with A=zyb, B=zxb so the
// output buffer is thetaT[j_theta][i_theta] (theta transposed) at zero cost.
__global__ __launch_bounds__(256) void gemm_bt(
        const __bf16* __restrict__ Abf, const __bf16* __restrict__ Bbf,
        float* __restrict__ theta) {
    __shared__ __bf16 As[64 * 40];
    __shared__ __bf16 Bs[64 * 40];
    const int b = blockIdx.z;
    const int i0 = blockIdx.y * 64, j0 = blockIdx.x * 64;
    const __bf16* ap = Abf + ((size_t)b * NN + i0) * DD;
    const __bf16* bp = Bbf + ((size_t)b * MM + j0) * DD;
    const int t = threadIdx.x;
    const int srow = t >> 2, scol = (t & 3) * 8;
    const int lane = t & 63, wave = t >> 6;
    const int mrow = lane & 15, quad = lane >> 4;
    v4f acc[4] = {};
    for (int kk = 0; kk < DD; kk += 32) {
        if (kk) __syncthreads();
        *(v8bf*)&As[srow * 40 + scol] = *(const v8bf*)(ap + (size_t)srow * DD + kk + scol);
        *(v8bf*)&Bs[srow * 40 + scol] = *(const v8bf*)(bp + (size_t)srow * DD + kk + scol);
        __syncthreads();
        v8bf af = *(const v8bf*)&As[(wave * 16 + mrow) * 40 + quad * 8];
        #pragma unroll
        for (int tt = 0; tt < 4; ++tt) {
            v8bf bf = *(const v8bf*)&Bs[(tt * 16 + mrow) * 40 + quad * 8];
            acc[tt] = __builtin_amdgcn_mfma_f32_16x16x32_bf16(af, bf, acc[tt], 0, 0, 0);
        }
    }
    const size_t tb = (size_t)b * NN * MM;
    #pragma unroll
    for (int tt = 0; tt < 4; ++tt) {
        int j = j0 + tt * 16 + mrow;
        #pragma unroll
        for (int r = 0; r < 4; ++r) {
            int i = i0 + wave * 16 + quad * 4 + r;
            theta[tb + (size_t)i * MM + j] = acc[tt][r];
        }
    }
}

// --------------------------------------------------- soft-NW wavefront DP
// 8 waves per batch (512 threads => 2 waves/SIMD: a wave's chain latency is
// hidden by the co-resident wave's issue). Wave w owns V-rows 128w+1..128w+128,
// lane t owns 2 rows. Wave w staggered DSTAG=96 cols behind wave w-1; boundary
// crosses waves via LDS ring; barrier every 32 iters. Write at iter c+96w-33
// (body), read at tail of iter c+96w-1 => 33-iter window always contains one
// barrier. Ring slot reused after 256 iters >> 33-iter lifetime.
// Cross-lane handoff via DPP wave_shr:1 (no LDS, no bpermute).
// Theta: 8-deep circular register prefetch (unroll-by-8).
__global__ __launch_bounds__(512) void nw_dp(
        const float* __restrict__ thetaT, const float* __restrict__ acc,
        const float* __restrict__ gap_b, float* __restrict__ out) {
    const int b = blockIdx.x;
    const int tid = threadIdx.x;
    const int t = tid & 63, w = tid >> 6;
    const float Ac = (acc[b] + gap_b[0]) * LOG2E;
    const float Ka = __builtin_amdgcn_exp2f(Ac);   // 2^Ac, |Ac| is O(1)
    const int row0 = w * 128 + t * 2;              // theta rows row0, row0+1
    const int off = w * DSTAG + t;                 // lane's column lag
    const float* Tb = thetaT + (size_t)b * NN * MM + row0;

    __shared__ float ring[NWAVE - 1][256];

    float v0 = NEGS, v1 = NEGS;                    // this lane's two rows, col c-1
    float vbc = NEGS, vbp = NEGS;                  // bottom-row value, iter-1 / iter-2

    float2 pf[PF];
    #pragma unroll
    for (int u = 0; u < PF; ++u) {
        int c0 = u - off;
        c0 = c0 < 0 ? 0 : (c0 > MM - 1 ? MM - 1 : c0);
        pf[u] = *(const float2*)(Tb + (size_t)c0 * NN);
    }
    float rtc = NEGS, rtp = NEGS;                  // ring prefetch regs (lane 0, w>0)

    for (int gg = 0; gg < GTOT; gg += PF) {
        #pragma unroll
        for (int u = 0; u < PF; ++u) {
            const int g = gg + u;
            const int c = g - off;
            float tc = wave_shr1(vbc);
            float tp = wave_shr1(vbp);
            if (t == 0) {
                if (w == 0) { tc = NEGS; tp = (c == 0) ? 0.0f : NEGS; }
                else        { tc = rtc;  tp = (c == 0) ? NEGS : rtp; }
            }
            vbp = vbc;

            const float2 cur = pf[u];
            int cn = g + PF - off;
            cn = cn < 0 ? 0 : (cn > MM - 1 ? MM - 1 : cn);
            pf[u] = *(const float2*)(Tb + (size_t)cn * NN);

            if (c >= 0 && c < MM) {
                // cell 0: row row0+1 of V.  up_in=tc, diag=tp, left=v0
                float mx0 = fmaxf(fmaxf(tc, v0), tp);
                float e0a = __builtin_amdgcn_exp2f(tc - mx0);
                float e0b = __builtin_amdgcn_exp2f(v0 - mx0);
                float e0c = __builtin_amdgcn_exp2f(tp - mx0);
                float s0  = fmaf(Ka, e0a + e0b, e0c);
                float nv0 = fmaf(cur.x, LOG2E, mx0 + Ac + __builtin_amdgcn_logf(s0));
                // cell 1: up_in=nv0, diag=v0(old), left=v1
                float mx1 = fmaxf(fmaxf(nv0, v1), v0);
                float e1a = __builtin_amdgcn_exp2f(nv0 - mx1);
                float e1b = __builtin_amdgcn_exp2f(v1 - mx1);
                float e1c = __builtin_amdgcn_exp2f(v0 - mx1);
                float s1  = fmaf(Ka, e1a + e1b, e1c);
                float nv1 = fmaf(cur.y, LOG2E, mx1 + Ac + __builtin_amdgcn_logf(s1));
                v0 = nv0; v1 = nv1;
                vbc = nv1;
                if (t == 63 && w < NWAVE - 1) ring[w][c & 255] = nv1;
            }

            if ((g & (BARP - 1)) == (BARP - 1)) __syncthreads();

            // ring prefetch for iteration g+1; rtp is last iter's rtc.
            if (t == 0 && w > 0) {
                rtp = rtc;
                rtc = ring[w - 1][(g + 1 - off) & 255];
            }
        }
    }
    if (tid == NWAVE * 64 - 1) out[b] = v1 * LN2f;
}

// ---------------------------------------------------------------- launcher
extern "C" void kernel_launch(void* const* d_in, const int* in_sizes, int n_in,
                              void* d_out, int out_size, void* d_ws, size_t ws_size,
                              hipStream_t stream) {
    const float* zx    = (const float*)d_in[0];
    const float* zy    = (const float*)d_in[1];
    const float* gw    = (const float*)d_in[2];
    const float* gapb  = (const float*)d_in[3];
    float* out = (float*)d_out;

    char* ws = (char*)d_ws;
    float*  thetaT = (float*)ws;                                  // 67,108,864 B
    __bf16* zxb   = (__bf16*)(ws + (size_t)67108864);             // 16,777,216 B
    __bf16* zyb   = (__bf16*)(ws + (size_t)67108864 + 16777216);  // 16,777,216 B
    float*  acc   = (float*)(ws + (size_t)67108864 + 2 * 16777216);

    zero_acc<<<1, 64, 0, stream>>>(acc);
    conv_reduce<<<dim3(16, BATCH, 2), 256, 0, stream>>>(zx, zy, gw, zxb, zyb, acc);
    // swapped args: output = theta^T
    gemm_bt<<<dim3(MM / 64, NN / 64, BATCH), 256, 0, stream>>>(zyb, zxb, thetaT);
    nw_dp<<<BATCH, NWAVE * 64, 0, stream>>>(thetaT, acc, gapb, out);
}